// Round 1
// baseline (101.151 us; speedup 1.0000x reference)
//
#include <hip/hip_runtime.h>
#include <hip/hip_bf16.h>

// MoE token scatter: out[dest[t], :] = token_hidden[t, :] where
// dest[t] = expert_offsets[expert_idx[t]] + slot_idx[t].
// HIDDEN = 1024 fp32 per row = 256 float4 per row = one 256-thread block.

#define HIDDEN 1024
#define VEC 4               // float4
#define THREADS (HIDDEN / VEC)   // 256

__global__ __launch_bounds__(THREADS) void moe_scatter_kernel(
    const float* __restrict__ token_hidden,
    const int* __restrict__ expert_idx,
    const int* __restrict__ slot_idx,
    const int* __restrict__ expert_offsets,
    float* __restrict__ out) {
    const int t = blockIdx.x;
    const int e = expert_idx[t];
    const int dest = expert_offsets[e] + slot_idx[t];

    const float4* __restrict__ src =
        reinterpret_cast<const float4*>(token_hidden + (size_t)t * HIDDEN);
    float4* __restrict__ dst =
        reinterpret_cast<float4*>(out + (size_t)dest * HIDDEN);

    dst[threadIdx.x] = src[threadIdx.x];
}

extern "C" void kernel_launch(void* const* d_in, const int* in_sizes, int n_in,
                              void* d_out, int out_size, void* d_ws, size_t ws_size,
                              hipStream_t stream) {
    const float* token_hidden   = (const float*)d_in[0];
    const int*   expert_idx     = (const int*)d_in[1];
    const int*   slot_idx       = (const int*)d_in[2];
    const int*   expert_offsets = (const int*)d_in[3];
    float* out = (float*)d_out;

    const int num_tokens = in_sizes[1];  // expert_idx has one entry per token

    moe_scatter_kernel<<<num_tokens, THREADS, 0, stream>>>(
        token_hidden, expert_idx, slot_idx, expert_offsets, out);
}